// Round 3
// baseline (58.435 us; speedup 1.0000x reference)
//
#include <hip/hip_runtime.h>
#include <hip/hip_bf16.h>

#define Bn 2048
#define Dn 512

typedef __bf16 bf16x8 __attribute__((ext_vector_type(8)));
typedef float f32x4 __attribute__((ext_vector_type(4)));

union Pack8 { uint4 u; __hip_bfloat16 h[8]; };

typedef __attribute__((address_space(1))) const unsigned int gas_u32;
typedef __attribute__((address_space(3))) unsigned int las_u32;

__device__ __forceinline__ void gload16(const void* g, void* l) {
  __builtin_amdgcn_global_load_lds((gas_u32*)g, (las_u32*)l, 16, 0, 0);
}

// One block per row index: wave m normalizes row `blockIdx.x` of matrix m,
// writes bf16 to nm, keeps f32 in LDS, then computes the 6 pairwise diagonal
// dots. Also zeroes rs (first 72 blocks' worth of threads).
__global__ __launch_bounds__(256) void normalize_kernel(
    const float* __restrict__ in0, const float* __restrict__ in1,
    const float* __restrict__ in2, const float* __restrict__ in3,
    __hip_bfloat16* __restrict__ nm, float* __restrict__ rs, float* __restrict__ dd) {
  __shared__ float sv[4][Dn];
  __shared__ float red[4][6];
  int row = blockIdx.x;
  int wave = threadIdx.x >> 6, lane = threadIdx.x & 63;

  int g = blockIdx.x * 256 + threadIdx.x;
  if (g < 9 * Bn) rs[g] = 0.0f;

  const float* src =
      (wave == 0 ? in0 : wave == 1 ? in1 : wave == 2 ? in2 : in3) + (size_t)row * Dn;
  int k = lane * 8;
  float4 x0 = *(const float4*)(src + k);
  float4 x1 = *(const float4*)(src + k + 4);
  float v[8] = {x0.x, x0.y, x0.z, x0.w, x1.x, x1.y, x1.z, x1.w};
  float ss = 0.f;
#pragma unroll
  for (int e = 0; e < 8; e++) ss = fmaf(v[e], v[e], ss);
#pragma unroll
  for (int off = 1; off < 64; off <<= 1) ss += __shfl_xor(ss, off, 64);
  float scale = 1.0f / fmaxf(sqrtf(ss), 1e-8f);
  Pack8 pw;
#pragma unroll
  for (int e = 0; e < 8; e++) {
    float nv = v[e] * scale;
    pw.h[e] = __float2bfloat16(nv);
    sv[wave][k + e] = nv;
  }
  *(uint4*)(nm + (size_t)(wave * Bn + row) * Dn + k) = pw.u;
  __syncthreads();

  int t = threadIdx.x;
  float o0 = sv[0][2 * t], o1 = sv[0][2 * t + 1];
  float h0 = sv[1][2 * t], h1 = sv[1][2 * t + 1];
  float p0 = sv[2][2 * t], p1 = sv[2][2 * t + 1];
  float n0 = sv[3][2 * t], n1 = sv[3][2 * t + 1];
  float s[6];
  s[0] = fmaf(o0, h0, o1 * h1);
  s[1] = fmaf(o0, p0, o1 * p1);
  s[2] = fmaf(h0, p0, h1 * p1);
  s[3] = fmaf(o0, n0, o1 * n1);
  s[4] = fmaf(h0, n0, h1 * n1);
  s[5] = fmaf(p0, n0, p1 * n1);
#pragma unroll
  for (int off = 1; off < 64; off <<= 1) {
#pragma unroll
    for (int j = 0; j < 6; j++) s[j] += __shfl_xor(s[j], off, 64);
  }
  if (lane == 0) {
#pragma unroll
    for (int j = 0; j < 6; j++) red[wave][j] = s[j];
  }
  __syncthreads();
  if (threadIdx.x < 6) {
    int j = threadIdx.x;
    dd[j * Bn + row] = red[0][j] + red[1][j] + red[2][j] + red[3][j];
  }
}

// C = X * Y^T fused with e = exp(10c-10), row/col-sum accumulation.
// 128x128 tile, BK=32, double-buffered LDS, 2-phase pipeline:
//   barrier -> issue stage(t+1 -> buf^1) -> compute(buf)
// __syncthreads' vmcnt(0)+lgkm(0) drain IS the pipeline wait: the prefetch
// issued last iter is in flight during this iter's MFMA.
// Compact grid: 1176 blocks (3 sym pairs x 136 upper-tri + 3 cross x 256),
// bijective XCD chunking (1176 = 8*147).
#define BM 128
#define BK 32
#define NT (Dn / BK)

__global__ __launch_bounds__(256) void gemm_rowsum_kernel(const __hip_bfloat16* __restrict__ nm,
                                                          float* __restrict__ rs) {
  __shared__ __hip_bfloat16 As[2][BM * BK];
  __shared__ __hip_bfloat16 Bs[2][BM * BK];
  const int pxA[6] = {0, 1, 2, 0, 0, 1};
  const int pyA[6] = {0, 1, 2, 1, 2, 2};
  const int rrowA[6] = {0, 1, 2, 3, 5, 7};
  const int rcolA[6] = {0, 1, 2, 4, 6, 8};

  // flat id -> XCD-chunked logical id -> (z, by, bx)
  int id = ((int)blockIdx.x & 7) * 147 + ((int)blockIdx.x >> 3);
  int z, by, bx;
  if (id < 408) {
    z = id / 136;
    int t = id - z * 136;
    int byv = 0;
    while (t >= 16 - byv) { t -= 16 - byv; byv++; }
    by = byv;
    bx = byv + t;
  } else {
    int id2 = id - 408;
    z = 3 + (id2 >> 8);
    int t = id2 & 255;
    by = t >> 4;
    bx = t & 15;
  }
  bool sym = (z < 3);

  const __hip_bfloat16* X = nm + (size_t)pxA[z] * Bn * Dn;
  const __hip_bfloat16* Y = nm + (size_t)pyA[z] * Bn * Dn;
  int tid = threadIdx.x, lane = tid & 63, wave = tid >> 6;
  int wr = wave >> 1, wc = wave & 1;
  int c = lane & 15, rgrp = lane >> 4;

  // staging addresses: thread covers rows srow / srow+64, 8 elems at scol
  int srow = wave * 16 + (lane >> 2);
  int scol = (lane & 3) * 8;
  const __hip_bfloat16* gA = X + (size_t)(by * BM + srow) * Dn + scol;
  const __hip_bfloat16* gB = Y + (size_t)(bx * BM + srow) * Dn + scol;
  char* ldsA0 = (char*)&As[0][0] + wave * 1024;  // wave-uniform base; HW adds lane*16
  char* ldsB0 = (char*)&Bs[0][0] + wave * 1024;

  // prologue: stage k-step 0 into buffer 0
  gload16(gA, ldsA0);
  gload16(gA + (size_t)64 * Dn, ldsA0 + 4096);
  gload16(gB, ldsB0);
  gload16(gB + (size_t)64 * Dn, ldsB0 + 4096);

  f32x4 acc[4][4] = {};
  int cur = 0;
  for (int t = 0; t < NT; ++t) {
    __syncthreads();  // drains vmcnt(0): stage(t) complete; lgkm: prev reads done
    if (t + 1 < NT) {
      int k0 = (t + 1) * BK;
      char* dA = ldsA0 + (cur ^ 1) * (BM * BK * 2);
      char* dB = ldsB0 + (cur ^ 1) * (BM * BK * 2);
      gload16(gA + k0, dA);
      gload16(gA + k0 + (size_t)64 * Dn, dA + 4096);
      gload16(gB + k0, dB);
      gload16(gB + k0 + (size_t)64 * Dn, dB + 4096);
    }
    const char* bA = (const char*)&As[cur][0];
    const char* bB = (const char*)&Bs[cur][0];
    bf16x8 a[4], b[4];
#pragma unroll
    for (int mi = 0; mi < 4; mi++)
      a[mi] = *(const bf16x8*)(bA + (wr * 64 + mi * 16 + c) * (BK * 2) + rgrp * 16);
#pragma unroll
    for (int ni = 0; ni < 4; ni++)
      b[ni] = *(const bf16x8*)(bB + (wc * 64 + ni * 16 + c) * (BK * 2) + rgrp * 16);
#pragma unroll
    for (int mi = 0; mi < 4; mi++)
#pragma unroll
      for (int ni = 0; ni < 4; ni++)
        acc[mi][ni] = __builtin_amdgcn_mfma_f32_16x16x32_bf16(a[mi], b[ni], acc[mi][ni], 0, 0, 0);
    cur ^= 1;
  }

  // epilogue: exp in place (C/D: row = rgrp*4+r, col = c)
  bool skip_diag = sym && (by == bx);
#pragma unroll
  for (int mi = 0; mi < 4; mi++)
#pragma unroll
    for (int ni = 0; ni < 4; ni++)
#pragma unroll
      for (int r = 0; r < 4; r++) {
        int grow = by * BM + wr * 64 + mi * 16 + rgrp * 4 + r;
        int gcol = bx * BM + wc * 64 + ni * 16 + c;
        float e = __expf(10.0f * acc[mi][ni][r] - 10.0f);
        acc[mi][ni][r] = (skip_diag && grow == gcol) ? 0.0f : e;
      }

  float* rs_row = rs + rrowA[z] * Bn;
#pragma unroll
  for (int mi = 0; mi < 4; mi++)
#pragma unroll
    for (int r = 0; r < 4; r++) {
      float val = acc[mi][0][r] + acc[mi][1][r] + acc[mi][2][r] + acc[mi][3][r];
#pragma unroll
      for (int off = 1; off < 16; off <<= 1) val += __shfl_xor(val, off, 16);
      if (c == 0) atomicAdd(rs_row + by * BM + wr * 64 + mi * 16 + rgrp * 4 + r, val);
    }

  // col sums: cross pairs always; symmetric pairs only off-diagonal blocks
  if (!sym || (bx != by)) {
    float* rs_col = sym ? rs_row : rs + rcolA[z] * Bn;
#pragma unroll
    for (int ni = 0; ni < 4; ni++) {
      float val = 0.f;
#pragma unroll
      for (int mi = 0; mi < 4; mi++)
#pragma unroll
        for (int r = 0; r < 4; r++) val += acc[mi][ni][r];
      val += __shfl_xor(val, 16, 64);
      val += __shfl_xor(val, 32, 64);
      if (lane < 16) atomicAdd(rs_col + bx * BM + wc * 64 + ni * 16 + c, val);
    }
  }
}

// rs layout: 0:OO 1:HH 2:PP 3:OH 4:HO 5:OP 6:PO 7:HP 8:PH
// dd layout: 0:oh 1:op 2:hp 3:on 4:hn 5:pn
__global__ __launch_bounds__(1024) void final_kernel(const float* __restrict__ rs,
                                                     const float* __restrict__ dd,
                                                     float* __restrict__ out) {
  int tid = threadIdx.x;  // 1024
  float l1 = 0.f, l2 = 0.f, l3 = 0.f;
  for (int i = tid; i < Bn; i += 1024) {
    float doh = dd[i], dop = dd[Bn + i], dhp = dd[2 * Bn + i];
    float ea = __expf(10.0f * dd[3 * Bn + i] - 10.0f);
    float eb = __expf(10.0f * dd[4 * Bn + i] - 10.0f);
    float ec = __expf(10.0f * dd[5 * Bn + i] - 10.0f);
    float r0 = rs[i], r1 = rs[Bn + i], r2 = rs[2 * Bn + i];
    float r3 = rs[3 * Bn + i], r4 = rs[4 * Bn + i], r5 = rs[5 * Bn + i];
    float r6 = rs[6 * Bn + i], r7 = rs[7 * Bn + i], r8 = rs[8 * Bn + i];
    l1 += 20.0f + logf(r0 + r3 + ea) + logf(r4 + r1 + ea) - 20.0f * doh;
    l2 += 20.0f + logf(r0 + r5 + ea) + logf(r6 + r2 + ea) - 20.0f * dop;
    l3 += 20.0f + logf(r1 + r7 + eb + ec) + logf(r8 + r2 + eb + ec) - 20.0f * dhp;
  }
  __shared__ float red[3][1024];
  red[0][tid] = l1; red[1][tid] = l2; red[2][tid] = l3;
  __syncthreads();
  for (int s = 512; s > 0; s >>= 1) {
    if (tid < s) {
      red[0][tid] += red[0][tid + s];
      red[1][tid] += red[1][tid + s];
      red[2][tid] += red[2][tid + s];
    }
    __syncthreads();
  }
  if (tid == 0) {
    out[0] = red[0][0] / 4096.0f;
    out[1] = red[1][0] / 4096.0f;
    out[2] = red[2][0] / 4096.0f;
  }
}

extern "C" void kernel_launch(void* const* d_in, const int* in_sizes, int n_in,
                              void* d_out, int out_size, void* d_ws, size_t ws_size,
                              hipStream_t stream) {
  const float* z0 = (const float*)d_in[0];
  const float* z1 = (const float*)d_in[1];
  const float* z2 = (const float*)d_in[2];
  const float* z3 = (const float*)d_in[3];
  float* out = (float*)d_out;

  __hip_bfloat16* nm = (__hip_bfloat16*)d_ws;                   // 4*2048*512 bf16 = 8 MB
  float* rs = (float*)((char*)d_ws + (size_t)4 * Bn * Dn * 2);  // 9*2048 f32
  float* dd = rs + 9 * Bn;                                      // 6*2048 f32

  hipLaunchKernelGGL(normalize_kernel, dim3(2048), dim3(256), 0, stream,
                     z0, z1, z2, z3, nm, rs, dd);
  hipLaunchKernelGGL(gemm_rowsum_kernel, dim3(1176), dim3(256), 0, stream, nm, rs);
  hipLaunchKernelGGL(final_kernel, dim3(1), dim3(1024), 0, stream, rs, dd, out);
}

// Round 4
// 53.877 us; speedup vs baseline: 1.0846x; 1.0846x over previous
//
#include <hip/hip_runtime.h>
#include <hip/hip_bf16.h>

#define Bn 2048
#define Dn 512

typedef float f32x4 __attribute__((ext_vector_type(4)));

// One block per row index: wave m normalizes row `blockIdx.x` of matrix m
// (0:O 1:H 2:P 3:N), writes fp8-e4m3 (O,H,P only) to nm8, keeps f32 in LDS,
// then computes the 6 pairwise diagonal dots in f32. Also zeroes rs.
__global__ __launch_bounds__(256) void normalize_kernel(
    const float* __restrict__ in0, const float* __restrict__ in1,
    const float* __restrict__ in2, const float* __restrict__ in3,
    unsigned char* __restrict__ nm8, float* __restrict__ rs, float* __restrict__ dd) {
  __shared__ float sv[4][Dn];
  __shared__ float red[4][6];
  int row = blockIdx.x;
  int wave = threadIdx.x >> 6, lane = threadIdx.x & 63;

  int g = blockIdx.x * 256 + threadIdx.x;
  if (g < 9 * Bn) rs[g] = 0.0f;

  const float* src =
      (wave == 0 ? in0 : wave == 1 ? in1 : wave == 2 ? in2 : in3) + (size_t)row * Dn;
  int k = lane * 8;
  float4 x0 = *(const float4*)(src + k);
  float4 x1 = *(const float4*)(src + k + 4);
  float v[8] = {x0.x, x0.y, x0.z, x0.w, x1.x, x1.y, x1.z, x1.w};
  float ss = 0.f;
#pragma unroll
  for (int e = 0; e < 8; e++) ss = fmaf(v[e], v[e], ss);
#pragma unroll
  for (int off = 1; off < 64; off <<= 1) ss += __shfl_xor(ss, off, 64);
  float scale = 1.0f / fmaxf(sqrtf(ss), 1e-8f);
  float nv[8];
#pragma unroll
  for (int e = 0; e < 8; e++) {
    nv[e] = v[e] * scale;
    sv[wave][k + e] = nv[e];
  }
  if (wave < 3) {
    // pack 8 fp8 e4m3 (RNE, handles denormals in HW)
    unsigned int lo = __builtin_amdgcn_cvt_pk_fp8_f32(nv[0], nv[1], 0u, false);
    lo = __builtin_amdgcn_cvt_pk_fp8_f32(nv[2], nv[3], lo, true);
    unsigned int hi = __builtin_amdgcn_cvt_pk_fp8_f32(nv[4], nv[5], 0u, false);
    hi = __builtin_amdgcn_cvt_pk_fp8_f32(nv[6], nv[7], hi, true);
    uint2 pk; pk.x = lo; pk.y = hi;
    *(uint2*)(nm8 + ((size_t)wave * Bn + row) * Dn + k) = pk;
  }
  __syncthreads();

  int t = threadIdx.x;
  float o0 = sv[0][2 * t], o1 = sv[0][2 * t + 1];
  float h0 = sv[1][2 * t], h1 = sv[1][2 * t + 1];
  float p0 = sv[2][2 * t], p1 = sv[2][2 * t + 1];
  float n0 = sv[3][2 * t], n1 = sv[3][2 * t + 1];
  float s[6];
  s[0] = fmaf(o0, h0, o1 * h1);
  s[1] = fmaf(o0, p0, o1 * p1);
  s[2] = fmaf(h0, p0, h1 * p1);
  s[3] = fmaf(o0, n0, o1 * n1);
  s[4] = fmaf(h0, n0, h1 * n1);
  s[5] = fmaf(p0, n0, p1 * n1);
#pragma unroll
  for (int off = 1; off < 64; off <<= 1) {
#pragma unroll
    for (int j = 0; j < 6; j++) s[j] += __shfl_xor(s[j], off, 64);
  }
  if (lane == 0) {
#pragma unroll
    for (int j = 0; j < 6; j++) red[wave][j] = s[j];
  }
  __syncthreads();
  if (threadIdx.x < 6) {
    int j = threadIdx.x;
    dd[j * Bn + row] = red[0][j] + red[1][j] + red[2][j] + red[3][j];
  }
}

// Unified Gram over M = [O;H;P] (6144x512 fp8). Upper-tri 128^2 tiles: 1176
// blocks. Whole K resident: 2 chunks of (A-half 32KB + B-half 32KB), staged
// via regs with a both-sides 16B XOR swizzle (u ^= row&15) -> conflict-free
// frag reads. 8 waves: quadrant q = w&3 (2x2 of 64x64), K-half h = w>>2;
// halves combined through LDS. Epilogue: exp(10c-10), row/col-sum atomics.
__global__ __launch_bounds__(512, 4) void gemm_fp8_kernel(const unsigned char* __restrict__ nm8,
                                                          float* __restrict__ rs) {
  __shared__ unsigned char lds[65536];  // [0,32K) A, [32K,64K) B; reused for combine

  // XCD-chunked flat id -> upper-tri (by <= bx) over 48x48
  int id = ((int)blockIdx.x & 7) * 147 + ((int)blockIdx.x >> 3);
  int by = 0, rem = id, cnt = 48;
  while (rem >= cnt) { rem -= cnt; by++; cnt--; }
  int bx = by + rem;
  int u = by >> 4, v = bx >> 4;
  int rrow, rcol;
  if (u == v) { rrow = u; rcol = u; }
  else if (u == 0) { if (v == 1) { rrow = 3; rcol = 4; } else { rrow = 5; rcol = 6; } }
  else { rrow = 7; rcol = 8; }

  const unsigned char* gA = nm8 + ((size_t)u * Bn + (size_t)(by & 15) * 128) * Dn;
  const unsigned char* gB = nm8 + ((size_t)v * Bn + (size_t)(bx & 15) * 128) * Dn;

  int tid = threadIdx.x, lane = tid & 63, w = tid >> 6;
  int q = w & 3, h = w >> 2, qm = q >> 1, qn = q & 1;
  int c = lane & 15, rgrp = lane >> 4;

  f32x4 acc[4][4] = {};

  for (int kc = 0; kc < 2; ++kc) {
    __syncthreads();  // previous chunk's reads complete before overwrite
    // stage 64KB: 2 segments (A,B) x 4 rounds of 512 thr x 16B
#pragma unroll
    for (int jb = 0; jb < 2; ++jb) {
      const unsigned char* gsrc = (jb == 0) ? gA : gB;
      uint4 tmp[4];
#pragma unroll
      for (int j2 = 0; j2 < 4; ++j2) {
        int o = (j2 * 512 + tid) * 16;        // 0..32KB within segment
        int srow = o >> 8;                    // 0..127
        int uu = (o >> 4) & 15;               // 16B unit within 256B row-half
        tmp[j2] = *(const uint4*)(gsrc + (size_t)srow * Dn + kc * 256 + uu * 16);
      }
#pragma unroll
      for (int j2 = 0; j2 < 4; ++j2) {
        int o = (j2 * 512 + tid) * 16;
        int srow = o >> 8;
        int uu = (o >> 4) & 15;
        *(uint4*)(lds + jb * 32768 + srow * 256 + ((uu ^ (srow & 15)) << 4)) = tmp[j2];
      }
    }
    __syncthreads();  // stage visible to all

    const unsigned char* As = lds;
    const unsigned char* Bs = lds + 32768;
#pragma unroll
    for (int s = 0; s < 4; ++s) {
      int ksl = h * 4 + s;                    // local k-step (32 fp8 elems)
      int ub = ksl * 2 + (rgrp >> 1);         // 16B unit index pre-swizzle
      int inner = (rgrp & 1) * 8;
      long long a[4], b[4];
#pragma unroll
      for (int mi = 0; mi < 4; ++mi) {
        int r0 = qm * 64 + mi * 16 + c;       // row&15 == c
        a[mi] = *(const long long*)(As + r0 * 256 + ((ub ^ c) << 4) + inner);
      }
#pragma unroll
      for (int ni = 0; ni < 4; ++ni) {
        int r0 = qn * 64 + ni * 16 + c;
        b[ni] = *(const long long*)(Bs + r0 * 256 + ((ub ^ c) << 4) + inner);
      }
#pragma unroll
      for (int mi = 0; mi < 4; ++mi)
#pragma unroll
        for (int ni = 0; ni < 4; ++ni)
          acc[mi][ni] =
              __builtin_amdgcn_mfma_f32_16x16x32_fp8_fp8(a[mi], b[ni], acc[mi][ni], 0, 0, 0);
    }
  }

  // combine K-halves: h==1 dumps to LDS (reuses tile space), h==0 adds
  __syncthreads();
  if (h == 1) {
#pragma unroll
    for (int mi = 0; mi < 4; ++mi)
#pragma unroll
      for (int ni = 0; ni < 4; ++ni)
        *(f32x4*)(lds + q * 16384 + (mi * 4 + ni) * 1024 + lane * 16) = acc[mi][ni];
  }
  __syncthreads();
  if (h == 0) {
#pragma unroll
    for (int mi = 0; mi < 4; ++mi)
#pragma unroll
      for (int ni = 0; ni < 4; ++ni)
        acc[mi][ni] += *(const f32x4*)(lds + q * 16384 + (mi * 4 + ni) * 1024 + lane * 16);

    // epilogue: exp (C/D layout: row = rgrp*4+r, col = c), diag skip on by==bx
    bool skip_diag = (by == bx);
#pragma unroll
    for (int mi = 0; mi < 4; ++mi)
#pragma unroll
      for (int ni = 0; ni < 4; ++ni)
#pragma unroll
        for (int r = 0; r < 4; ++r) {
          int grow = qm * 64 + mi * 16 + rgrp * 4 + r;
          int gcol = qn * 64 + ni * 16 + c;
          float e = __expf(10.0f * acc[mi][ni][r] - 10.0f);
          acc[mi][ni][r] = (skip_diag && grow == gcol) ? 0.0f : e;
        }

    float* rs_row = rs + rrow * Bn + (by & 15) * 128;
#pragma unroll
    for (int mi = 0; mi < 4; ++mi)
#pragma unroll
      for (int r = 0; r < 4; ++r) {
        float val = acc[mi][0][r] + acc[mi][1][r] + acc[mi][2][r] + acc[mi][3][r];
#pragma unroll
        for (int off = 1; off < 16; off <<= 1) val += __shfl_xor(val, off, 16);
        if (c == 0) atomicAdd(rs_row + qm * 64 + mi * 16 + rgrp * 4 + r, val);
      }

    if (by != bx) {  // col sums (mirror for sym, transpose array for cross)
      float* rs_col = rs + rcol * Bn + (bx & 15) * 128;
#pragma unroll
      for (int ni = 0; ni < 4; ++ni) {
        float val = 0.f;
#pragma unroll
        for (int mi = 0; mi < 4; ++mi)
#pragma unroll
          for (int r = 0; r < 4; ++r) val += acc[mi][ni][r];
        val += __shfl_xor(val, 16, 64);
        val += __shfl_xor(val, 32, 64);
        if (lane < 16) atomicAdd(rs_col + qn * 64 + ni * 16 + c, val);
      }
    }
  }
}

// rs layout: 0:OO 1:HH 2:PP 3:OH 4:HO 5:OP 6:PO 7:HP 8:PH
// dd layout: 0:oh 1:op 2:hp 3:on 4:hn 5:pn
__global__ __launch_bounds__(1024) void final_kernel(const float* __restrict__ rs,
                                                     const float* __restrict__ dd,
                                                     float* __restrict__ out) {
  int tid = threadIdx.x;  // 1024
  float l1 = 0.f, l2 = 0.f, l3 = 0.f;
  for (int i = tid; i < Bn; i += 1024) {
    float doh = dd[i], dop = dd[Bn + i], dhp = dd[2 * Bn + i];
    float ea = __expf(10.0f * dd[3 * Bn + i] - 10.0f);
    float eb = __expf(10.0f * dd[4 * Bn + i] - 10.0f);
    float ec = __expf(10.0f * dd[5 * Bn + i] - 10.0f);
    float r0 = rs[i], r1 = rs[Bn + i], r2 = rs[2 * Bn + i];
    float r3 = rs[3 * Bn + i], r4 = rs[4 * Bn + i], r5 = rs[5 * Bn + i];
    float r6 = rs[6 * Bn + i], r7 = rs[7 * Bn + i], r8 = rs[8 * Bn + i];
    l1 += 20.0f + logf(r0 + r3 + ea) + logf(r4 + r1 + ea) - 20.0f * doh;
    l2 += 20.0f + logf(r0 + r5 + ea) + logf(r6 + r2 + ea) - 20.0f * dop;
    l3 += 20.0f + logf(r1 + r7 + eb + ec) + logf(r8 + r2 + eb + ec) - 20.0f * dhp;
  }
  __shared__ float red[3][1024];
  red[0][tid] = l1; red[1][tid] = l2; red[2][tid] = l3;
  __syncthreads();
  for (int s = 512; s > 0; s >>= 1) {
    if (tid < s) {
      red[0][tid] += red[0][tid + s];
      red[1][tid] += red[1][tid + s];
      red[2][tid] += red[2][tid + s];
    }
    __syncthreads();
  }
  if (tid == 0) {
    out[0] = red[0][0] / 4096.0f;
    out[1] = red[1][0] / 4096.0f;
    out[2] = red[2][0] / 4096.0f;
  }
}

extern "C" void kernel_launch(void* const* d_in, const int* in_sizes, int n_in,
                              void* d_out, int out_size, void* d_ws, size_t ws_size,
                              hipStream_t stream) {
  const float* z0 = (const float*)d_in[0];
  const float* z1 = (const float*)d_in[1];
  const float* z2 = (const float*)d_in[2];
  const float* z3 = (const float*)d_in[3];
  float* out = (float*)d_out;

  unsigned char* nm8 = (unsigned char*)d_ws;                    // 3*2048*512 fp8 = 3 MB
  float* rs = (float*)((char*)d_ws + (size_t)3 * Bn * Dn);      // 9*2048 f32
  float* dd = rs + 9 * Bn;                                      // 6*2048 f32

  hipLaunchKernelGGL(normalize_kernel, dim3(2048), dim3(256), 0, stream,
                     z0, z1, z2, z3, nm8, rs, dd);
  hipLaunchKernelGGL(gemm_fp8_kernel, dim3(1176), dim3(512), 0, stream, nm8, rs);
  hipLaunchKernelGGL(final_kernel, dim3(1), dim3(1024), 0, stream, rs, dd, out);
}

// Round 5
// 47.782 us; speedup vs baseline: 1.2229x; 1.1276x over previous
//
#include <hip/hip_runtime.h>
#include <hip/hip_bf16.h>

#define Bn 2048
#define Dn 512

typedef float f32x4 __attribute__((ext_vector_type(4)));

typedef __attribute__((address_space(1))) const unsigned int gas_u32;
typedef __attribute__((address_space(3))) unsigned int las_u32;

__device__ __forceinline__ void gload16(const void* g, void* l) {
  __builtin_amdgcn_global_load_lds((gas_u32*)g, (las_u32*)l, 16, 0, 0);
}

// One block per row index: wave m normalizes row `blockIdx.x` of matrix m
// (0:O 1:H 2:P 3:N), writes fp8-e4m3 (O,H,P only) to nm8, keeps f32 in LDS,
// then computes the 6 pairwise diagonal dots in f32. Also zeroes rs.
__global__ __launch_bounds__(256) void normalize_kernel(
    const float* __restrict__ in0, const float* __restrict__ in1,
    const float* __restrict__ in2, const float* __restrict__ in3,
    unsigned char* __restrict__ nm8, float* __restrict__ rs, float* __restrict__ dd) {
  __shared__ float sv[4][Dn];
  __shared__ float red[4][6];
  int row = blockIdx.x;
  int wave = threadIdx.x >> 6, lane = threadIdx.x & 63;

  int g = blockIdx.x * 256 + threadIdx.x;
  if (g < 9 * Bn) rs[g] = 0.0f;

  const float* src =
      (wave == 0 ? in0 : wave == 1 ? in1 : wave == 2 ? in2 : in3) + (size_t)row * Dn;
  int k = lane * 8;
  float4 x0 = *(const float4*)(src + k);
  float4 x1 = *(const float4*)(src + k + 4);
  float v[8] = {x0.x, x0.y, x0.z, x0.w, x1.x, x1.y, x1.z, x1.w};
  float ss = 0.f;
#pragma unroll
  for (int e = 0; e < 8; e++) ss = fmaf(v[e], v[e], ss);
#pragma unroll
  for (int off = 1; off < 64; off <<= 1) ss += __shfl_xor(ss, off, 64);
  float scale = 1.0f / fmaxf(sqrtf(ss), 1e-8f);
  float nv[8];
#pragma unroll
  for (int e = 0; e < 8; e++) {
    nv[e] = v[e] * scale;
    sv[wave][k + e] = nv[e];
  }
  if (wave < 3) {
    unsigned int lo = __builtin_amdgcn_cvt_pk_fp8_f32(nv[0], nv[1], 0u, false);
    lo = __builtin_amdgcn_cvt_pk_fp8_f32(nv[2], nv[3], lo, true);
    unsigned int hi = __builtin_amdgcn_cvt_pk_fp8_f32(nv[4], nv[5], 0u, false);
    hi = __builtin_amdgcn_cvt_pk_fp8_f32(nv[6], nv[7], hi, true);
    uint2 pk; pk.x = lo; pk.y = hi;
    *(uint2*)(nm8 + ((size_t)wave * Bn + row) * Dn + k) = pk;
  }
  __syncthreads();

  int t = threadIdx.x;
  float o0 = sv[0][2 * t], o1 = sv[0][2 * t + 1];
  float h0 = sv[1][2 * t], h1 = sv[1][2 * t + 1];
  float p0 = sv[2][2 * t], p1 = sv[2][2 * t + 1];
  float n0 = sv[3][2 * t], n1 = sv[3][2 * t + 1];
  float s[6];
  s[0] = fmaf(o0, h0, o1 * h1);
  s[1] = fmaf(o0, p0, o1 * p1);
  s[2] = fmaf(h0, p0, h1 * p1);
  s[3] = fmaf(o0, n0, o1 * n1);
  s[4] = fmaf(h0, n0, h1 * n1);
  s[5] = fmaf(p0, n0, p1 * n1);
#pragma unroll
  for (int off = 1; off < 64; off <<= 1) {
#pragma unroll
    for (int j = 0; j < 6; j++) s[j] += __shfl_xor(s[j], off, 64);
  }
  if (lane == 0) {
#pragma unroll
    for (int j = 0; j < 6; j++) red[wave][j] = s[j];
  }
  __syncthreads();
  if (threadIdx.x < 6) {
    int j = threadIdx.x;
    dd[j * Bn + row] = red[0][j] + red[1][j] + red[2][j] + red[3][j];
  }
}

// Pipelined fp8 Gram kernel over M = [O;H;P] (6144x512). Upper-tri 128^2
// tiles: 1176 blocks, XCD-chunked. 8 waves (2x4), each owns a 64x32 output
// with full K. K split into 8 tiles of 64B; 3-deep LDS ring (48KB).
// Per phase: ds_read frags(t) | issue gload_lds(t+2) | 16 MFMA (setprio) |
// s_waitcnt vmcnt(2) | s_barrier.  Loads stay in flight across barriers.
// Even-XOR swizzle (u8 ^= ((row>>1)&3)<<1) pre-applied on the GLOBAL source
// (gload_lds dest is linear), inverted on the ds_read side -> conflict-free.
#define GBM 128
#define GBK 64
#define NKT 8
#define NBUF 3

__global__ __launch_bounds__(512, 6) void gemm_fp8_kernel(const unsigned char* __restrict__ nm8,
                                                          float* __restrict__ rs) {
  __shared__ unsigned char lds[NBUF * 16384];

  // XCD-chunked flat id -> upper-tri (by <= bx) over 48x48
  int id = ((int)blockIdx.x & 7) * 147 + ((int)blockIdx.x >> 3);
  int by = 0, rem = id, cnt = 48;
  while (rem >= cnt) { rem -= cnt; by++; cnt--; }
  int bx = by + rem;
  int u = by >> 4, v = bx >> 4;
  int rrow, rcol;
  if (u == v) { rrow = u; rcol = u; }
  else if (u == 0) { if (v == 1) { rrow = 3; rcol = 4; } else { rrow = 5; rcol = 6; } }
  else { rrow = 7; rcol = 8; }

  const unsigned char* gA = nm8 + ((size_t)u * Bn + (size_t)(by & 15) * GBM) * Dn;
  const unsigned char* gB = nm8 + ((size_t)v * Bn + (size_t)(bx & 15) * GBM) * Dn;

  int tid = threadIdx.x, lane = tid & 63, wave = tid >> 6;
  int wr = wave >> 2, wc = wave & 3;           // 2 x 4 wave grid
  int c = lane & 15, rgrp = lane >> 4;
  int xc = ((c >> 1) & 3) << 1;                // read-side XOR (row&15 == c)

  // staging: thread stages LDS bytes [tid*16, +16) of each 8KB half-tile
  int srow = tid >> 2;                          // 0..127
  int sx = ((srow >> 1) & 3) << 1;
  int su = ((tid & 3) << 1) ^ sx;               // source 8B-unit (even)
  const unsigned char* sA = gA + (size_t)srow * Dn + su * 8;
  const unsigned char* sB = gB + (size_t)srow * Dn + su * 8;
  int woff = wave << 10;                        // wave-uniform LDS dest base

  f32x4 acc[4][2] = {};

  // prologue: issue tiles 0,1 (4 loads/wave in flight)
  gload16(sA, lds + woff);
  gload16(sB, lds + 8192 + woff);
  gload16(sA + GBK, lds + 16384 + woff);
  gload16(sB + GBK, lds + 16384 + 8192 + woff);
  asm volatile("s_waitcnt vmcnt(2)" ::: "memory");  // tile 0 landed
  __builtin_amdgcn_s_barrier();
  asm volatile("" ::: "memory");

#pragma unroll
  for (int t = 0; t < NKT; ++t) {
    const int j = t % NBUF;
    const unsigned char* As = lds + j * 16384;
    const unsigned char* Bs = As + 8192;
    long long a[2][4], b[2][2];
#pragma unroll
    for (int ks = 0; ks < 2; ++ks) {
      int ub = (ks * 4 + rgrp) ^ xc;
#pragma unroll
      for (int mi = 0; mi < 4; ++mi)
        a[ks][mi] = *(const long long*)(As + (wr * 64 + mi * 16 + c) * 64 + ub * 8);
#pragma unroll
      for (int ni = 0; ni < 2; ++ni)
        b[ks][ni] = *(const long long*)(Bs + (wc * 32 + ni * 16 + c) * 64 + ub * 8);
    }
    if (t + 2 < NKT) {  // prefetch tile t+2 into the buffer freed last phase
      const int j2 = (t + 2) % NBUF;
      gload16(sA + (t + 2) * GBK, lds + j2 * 16384 + woff);
      gload16(sB + (t + 2) * GBK, lds + j2 * 16384 + 8192 + woff);
    }
    __builtin_amdgcn_s_setprio(1);
#pragma unroll
    for (int ks = 0; ks < 2; ++ks)
#pragma unroll
      for (int mi = 0; mi < 4; ++mi)
#pragma unroll
        for (int ni = 0; ni < 2; ++ni)
          acc[mi][ni] =
              __builtin_amdgcn_mfma_f32_16x16x32_fp8_fp8(a[ks][mi], b[ks][ni], acc[mi][ni], 0, 0, 0);
    __builtin_amdgcn_s_setprio(0);
    if (t + 2 < NKT) {
      asm volatile("s_waitcnt vmcnt(2)" ::: "memory");  // tile t+1 landed; t+2 in flight
    } else if (t == NKT - 2) {
      asm volatile("s_waitcnt vmcnt(0)" ::: "memory");  // drain last tile
    }
    __builtin_amdgcn_s_barrier();
    asm volatile("" ::: "memory");
    __builtin_amdgcn_sched_barrier(0);
  }

  // ---- epilogue: exp + block-level row/col combine in LDS, then atomics ----
  float* crow = (float*)lds;          // [128] row partials
  float* ccol = crow + GBM;           // [128] col partials
  __syncthreads();
  if (tid < 2 * GBM) ((float*)lds)[tid] = 0.0f;
  __syncthreads();

  bool skip_diag = (by == bx);
#pragma unroll
  for (int mi = 0; mi < 4; ++mi)
#pragma unroll
    for (int ni = 0; ni < 2; ++ni)
#pragma unroll
      for (int r = 0; r < 4; ++r) {
        int lrow = wr * 64 + mi * 16 + rgrp * 4 + r;
        int lcol = wc * 32 + ni * 16 + c;
        float e = __expf(10.0f * acc[mi][ni][r] - 10.0f);
        acc[mi][ni][r] = (skip_diag && lrow == lcol) ? 0.0f : e;
      }

#pragma unroll
  for (int mi = 0; mi < 4; ++mi)
#pragma unroll
    for (int r = 0; r < 4; ++r) {
      float val = acc[mi][0][r] + acc[mi][1][r];
      val += __shfl_xor(val, 1, 64);
      val += __shfl_xor(val, 2, 64);
      val += __shfl_xor(val, 4, 64);
      val += __shfl_xor(val, 8, 64);
      if (c == 0) atomicAdd(&crow[wr * 64 + mi * 16 + rgrp * 4 + r], val);
    }
#pragma unroll
  for (int ni = 0; ni < 2; ++ni) {
    float cv = 0.f;
#pragma unroll
    for (int mi = 0; mi < 4; ++mi)
#pragma unroll
      for (int r = 0; r < 4; ++r) cv += acc[mi][ni][r];
    cv += __shfl_xor(cv, 16, 64);
    cv += __shfl_xor(cv, 32, 64);
    if (lane < 16) atomicAdd(&ccol[wc * 32 + ni * 16 + c], cv);
  }
  __syncthreads();

  float* rs_row = rs + rrow * Bn + (by & 15) * GBM;
  if (tid < GBM) {
    atomicAdd(rs_row + tid, crow[tid]);
  } else if (tid < 2 * GBM && by != bx) {
    // sym off-diag mirrors into the same array (rcol==rrow); cross pairs go
    // to the transpose array.
    float* rs_col = rs + rcol * Bn + (bx & 15) * GBM;
    atomicAdd(rs_col + (tid - GBM), ccol[tid - GBM]);
  }
}

// rs layout: 0:OO 1:HH 2:PP 3:OH 4:HO 5:OP 6:PO 7:HP 8:PH
// dd layout: 0:oh 1:op 2:hp 3:on 4:hn 5:pn
__global__ __launch_bounds__(1024) void final_kernel(const float* __restrict__ rs,
                                                     const float* __restrict__ dd,
                                                     float* __restrict__ out) {
  int tid = threadIdx.x;  // 1024
  float l1 = 0.f, l2 = 0.f, l3 = 0.f;
  for (int i = tid; i < Bn; i += 1024) {
    float doh = dd[i], dop = dd[Bn + i], dhp = dd[2 * Bn + i];
    float ea = __expf(10.0f * dd[3 * Bn + i] - 10.0f);
    float eb = __expf(10.0f * dd[4 * Bn + i] - 10.0f);
    float ec = __expf(10.0f * dd[5 * Bn + i] - 10.0f);
    float r0 = rs[i], r1 = rs[Bn + i], r2 = rs[2 * Bn + i];
    float r3 = rs[3 * Bn + i], r4 = rs[4 * Bn + i], r5 = rs[5 * Bn + i];
    float r6 = rs[6 * Bn + i], r7 = rs[7 * Bn + i], r8 = rs[8 * Bn + i];
    l1 += 20.0f + logf(r0 + r3 + ea) + logf(r4 + r1 + ea) - 20.0f * doh;
    l2 += 20.0f + logf(r0 + r5 + ea) + logf(r6 + r2 + ea) - 20.0f * dop;
    l3 += 20.0f + logf(r1 + r7 + eb + ec) + logf(r8 + r2 + eb + ec) - 20.0f * dhp;
  }
  __shared__ float red[3][1024];
  red[0][tid] = l1; red[1][tid] = l2; red[2][tid] = l3;
  __syncthreads();
  for (int s = 512; s > 0; s >>= 1) {
    if (tid < s) {
      red[0][tid] += red[0][tid + s];
      red[1][tid] += red[1][tid + s];
      red[2][tid] += red[2][tid + s];
    }
    __syncthreads();
  }
  if (tid == 0) {
    out[0] = red[0][0] / 4096.0f;
    out[1] = red[1][0] / 4096.0f;
    out[2] = red[2][0] / 4096.0f;
  }
}

extern "C" void kernel_launch(void* const* d_in, const int* in_sizes, int n_in,
                              void* d_out, int out_size, void* d_ws, size_t ws_size,
                              hipStream_t stream) {
  const float* z0 = (const float*)d_in[0];
  const float* z1 = (const float*)d_in[1];
  const float* z2 = (const float*)d_in[2];
  const float* z3 = (const float*)d_in[3];
  float* out = (float*)d_out;

  unsigned char* nm8 = (unsigned char*)d_ws;                    // 3*2048*512 fp8 = 3 MB
  float* rs = (float*)((char*)d_ws + (size_t)3 * Bn * Dn);      // 9*2048 f32
  float* dd = rs + 9 * Bn;                                      // 6*2048 f32

  hipLaunchKernelGGL(normalize_kernel, dim3(2048), dim3(256), 0, stream,
                     z0, z1, z2, z3, nm8, rs, dd);
  hipLaunchKernelGGL(gemm_fp8_kernel, dim3(1176), dim3(512), 0, stream, nm8, rs);
  hipLaunchKernelGGL(final_kernel, dim3(1), dim3(1024), 0, stream, rs, dd, out);
}